// Round 7
// baseline (1322.581 us; speedup 1.0000x reference)
//
#include <hip/hip_runtime.h>

// FixPointLayer: z <- tanh(z @ W^T + x), B=8192, F=1024, 50 steps, fp32 out.
// Round 7 = round 6 with the xfr slot-mapping bug fixed: prep_xfr now uses
// the IDENTICAL bid->(mt,nt) XCD swizzle as fixpoint_gemm, so slot bid is
// consistent by construction. (Round 6 failed because prep wrote slots keyed
// by unswizzled (mt,nt) while the GEMM read slot bid under the swizzle.)
//   - 256 blocks (1/CU) x 512 thr; block tile 256x128; wave tile 64x64.
//   - per K-step: [post-MFMA barrier] -> issue next-tile stage (6 loads) ->
//     s_waitcnt vmcnt(6) -> [pre-MFMA barrier] -> ds_read + setprio MFMA x32.
//   - 96 KB dbuf LDS; XOR-preswizzled staging (0 bank conflicts, proven).

#define F 1024
#define NITER 50

typedef __attribute__((ext_vector_type(4))) _Float16 f16x4;
typedef __attribute__((ext_vector_type(8))) _Float16 f16x8;
typedef __attribute__((ext_vector_type(4))) float f32x4;

__device__ __forceinline__ float ftanh(float s) {
    float e = __expf(2.0f * s);
    return 1.0f - __fdividef(2.0f, e + 1.0f);
}

__device__ __forceinline__ void gload_lds16(const void* g, void* l) {
    __builtin_amdgcn_global_load_lds(
        (const __attribute__((address_space(1))) void*)g,
        (__attribute__((address_space(3))) void*)l, 16, 0, 0);
}

// shared bid -> (mt, nt) mapping (XCD mt-grouping swizzle)
__device__ __forceinline__ void tile_of(int bid, int& mt, int& nt) {
    const int xcd = bid & 7, q = bid >> 3;  // q: 0..31
    mt = xcd * 4 + (q & 3);                 // 0..31
    nt = q >> 2;                            // 0..7
}

// ---- W fp32 -> f16 ----
__global__ void prep_w(const float* __restrict__ W, _Float16* __restrict__ Wh) {
    int i = blockIdx.x * blockDim.x + threadIdx.x;
    float4 wv = ((const float4*)W)[i];
    f16x4 hv = {(_Float16)wv.x, (_Float16)wv.y, (_Float16)wv.z, (_Float16)wv.w};
    ((f16x4*)Wh)[i] = hv;
}

// ---- z0 = tanh(x) -> f16 ----
__global__ void prep_z0(const float* __restrict__ x, _Float16* __restrict__ zb0) {
    int i = blockIdx.x * blockDim.x + threadIdx.x;
    float4 xv = ((const float4*)x)[i];
    f16x4 zv = {(_Float16)ftanh(xv.x), (_Float16)ftanh(xv.y),
                (_Float16)ftanh(xv.z), (_Float16)ftanh(xv.w)};
    ((f16x4*)zb0)[i] = zv;
}

// ---- pack x into per-(block,thread) C-fragment order, f16 ----
// slot = bid (same swizzled mapping as fixpoint_gemm)
__global__ void prep_xfr(const float* __restrict__ x, _Float16* __restrict__ xfr) {
    const int bid = blockIdx.x;   // 256
    const int tid = threadIdx.x;  // 512
    int mt, nt;
    tile_of(bid, mt, nt);
    const int w = tid >> 6, l = tid & 63;
    const int wr = w >> 1, wc = w & 1;   // 4M x 2N wave grid
    const int kg = l >> 4, lc16 = l & 15;
    const int gm = mt * 256, gn = nt * 128;
    _Float16* dst = xfr + (((size_t)bid * 512 + tid) << 6);
#pragma unroll
    for (int m = 0; m < 4; ++m)
#pragma unroll
        for (int n = 0; n < 4; ++n) {
            f16x4 v;
#pragma unroll
            for (int j = 0; j < 4; ++j)
                v[j] = (_Float16)x[(size_t)(gm + wr * 64 + m * 16 + kg * 4 + j) * F
                                   + gn + wc * 64 + n * 16 + lc16];
            *(f16x4*)(dst + (m * 4 + n) * 4) = v;
        }
}

// stage 256x64 A-tile: 4 x 16B loads/thread; XOR-preswizzled source
__device__ __forceinline__ void stage_A(const _Float16* __restrict__ src,
                                        char* dst, int gm, int kb, int tid) {
    const int lc = tid & 7;
    const int rb = tid >> 3;  // 0..63
#pragma unroll
    for (int r = 0; r < 4; ++r) {
        int row = rb + r * 64;  // 0..255
        int cg = lc ^ (row & 7);
        gload_lds16(src + (size_t)(gm + row) * F + kb + cg * 8,
                    dst + row * 128 + lc * 16);
    }
}
// stage 128x64 B-tile: 2 x 16B loads/thread
__device__ __forceinline__ void stage_B(const _Float16* __restrict__ src,
                                        char* dst, int gn, int kb, int tid) {
    const int lc = tid & 7;
    const int rb = tid >> 3;
#pragma unroll
    for (int r = 0; r < 2; ++r) {
        int row = rb + r * 64;  // 0..127
        int cg = lc ^ (row & 7);
        gload_lds16(src + (size_t)(gn + row) * F + kb + cg * 8,
                    dst + row * 128 + lc * 16);
    }
}

__global__ __launch_bounds__(512, 2) void fixpoint_gemm(
    const _Float16* __restrict__ zin, _Float16* __restrict__ zout,
    const _Float16* __restrict__ Wh, const _Float16* __restrict__ xfr,
    const float* __restrict__ x32, float* __restrict__ out) {

    __shared__ __align__(16) char lds[98304];  // A: 2x32K, B: 2x16K
    char* const ab[2] = {lds, lds + 32768};
    char* const bb[2] = {lds + 65536, lds + 81920};

    const int tid = threadIdx.x;
    const int w = tid >> 6, l = tid & 63;
    const int wr = w >> 1, wc = w & 1;   // 4M x 2N waves; wave tile 64x64
    const int kg = l >> 4, lc16 = l & 15;
    const int bid = blockIdx.x;          // 256
    int mt, nt;
    tile_of(bid, mt, nt);
    const int gm = mt * 256, gn = nt * 128;

    // prologue: stage K-tile 0 (6 loads outstanding)
    stage_A(zin, ab[0], gm, 0, tid);
    stage_B(Wh, bb[0], gn, 0, tid);

    f32x4 acc[4][4];
#pragma unroll
    for (int m = 0; m < 4; ++m)
#pragma unroll
        for (int n = 0; n < 4; ++n) acc[m][n] = (f32x4){0.f, 0.f, 0.f, 0.f};

#pragma unroll
    for (int kt = 0; kt < 16; ++kt) {
        if (kt > 0) __builtin_amdgcn_s_barrier();  // retire step kt-1's reads
        // issue next tile BEFORE the wait (T4): lands under this step's MFMA.
        if (kt < 15) {
            stage_A(zin, ab[(kt + 1) & 1], gm, (kt + 1) * 64, tid);
            stage_B(Wh, bb[(kt + 1) & 1], gn, (kt + 1) * 64, tid);
            asm volatile("s_waitcnt vmcnt(6)" ::: "memory");  // tile-kt landed
        } else {
            asm volatile("s_waitcnt vmcnt(0)" ::: "memory");
        }
        __builtin_amdgcn_s_barrier();   // all waves' tile-kt loads landed
        asm volatile("" ::: "memory");  // no LDS reads hoist above barrier

        const char* A = ab[kt & 1];
        const char* B = bb[kt & 1];
#pragma unroll
        for (int kh = 0; kh < 2; ++kh) {
            const int sw = ((kh * 4 + kg) ^ (lc16 & 7)) << 4;
            f16x8 af[4], bf[4];
#pragma unroll
            for (int m = 0; m < 4; ++m)
                af[m] = *(const f16x8*)(A + (wr * 64 + m * 16 + lc16) * 128 + sw);
#pragma unroll
            for (int n = 0; n < 4; ++n)
                bf[n] = *(const f16x8*)(B + (wc * 64 + n * 16 + lc16) * 128 + sw);
            __builtin_amdgcn_s_setprio(1);
#pragma unroll
            for (int m = 0; m < 4; ++m)
#pragma unroll
                for (int n = 0; n < 4; ++n)
                    acc[m][n] = __builtin_amdgcn_mfma_f32_16x16x32_f16(
                        af[m], bf[n], acc[m][n], 0, 0, 0);
            __builtin_amdgcn_s_setprio(0);
        }
    }

    // ---- epilogue ----
    const bool lastit = (out != nullptr);
    if (!lastit) {
        _Float16 xl[64];
        {
            const f16x8* xp = (const f16x8*)(xfr + (((size_t)bid * 512 + tid) << 6));
#pragma unroll
            for (int qq = 0; qq < 8; ++qq) *(f16x8*)(xl + 8 * qq) = xp[qq];
        }
#pragma unroll
        for (int m = 0; m < 4; ++m)
#pragma unroll
            for (int j = 0; j < 4; ++j) {
                const size_t gr = gm + wr * 64 + m * 16 + kg * 4 + j;
#pragma unroll
                for (int n = 0; n < 4; ++n) {
                    const int gc = gn + wc * 64 + n * 16 + lc16;
                    zout[gr * F + gc] =
                        (_Float16)ftanh(acc[m][n][j] + (float)xl[(m * 4 + n) * 4 + j]);
                }
            }
    } else {
#pragma unroll
        for (int m = 0; m < 4; ++m)
#pragma unroll
            for (int j = 0; j < 4; ++j) {
                const size_t gr = gm + wr * 64 + m * 16 + kg * 4 + j;
#pragma unroll
                for (int n = 0; n < 4; ++n) {
                    const int gc = gn + wc * 64 + n * 16 + lc16;
                    out[gr * F + gc] = ftanh(acc[m][n][j] + x32[gr * F + gc]);
                }
            }
    }
}

extern "C" void kernel_launch(void* const* d_in, const int* in_sizes, int n_in,
                              void* d_out, int out_size, void* d_ws, size_t ws_size,
                              hipStream_t stream) {
    const float* x = (const float*)d_in[0];   // [8192,1024] fp32
    const float* W = (const float*)d_in[1];   // [1024,1024] fp32
    float* out = (float*)d_out;               // final fp32 output
    char* ws = (char*)d_ws;
    _Float16* zb0 = (_Float16*)ws;                   // 16 MiB
    _Float16* zb1 = (_Float16*)(ws + (16u << 20));   // 16 MiB
    _Float16* Wh  = (_Float16*)(ws + (32u << 20));   // 2 MiB
    _Float16* xfr = (_Float16*)(ws + (34u << 20));   // 16 MiB (total 50 MiB)

    prep_w<<<1024, 256, 0, stream>>>(W, Wh);
    prep_z0<<<8192, 256, 0, stream>>>(x, zb0);
    prep_xfr<<<256, 512, 0, stream>>>(x, xfr);
    for (int it = 1; it < NITER; ++it) {
        _Float16* zin  = (it & 1) ? zb0 : zb1;
        _Float16* zout = (it & 1) ? zb1 : zb0;
        bool last = (it == NITER - 1);
        fixpoint_gemm<<<256, 512, 0, stream>>>(zin, zout, Wh, xfr, x,
                                               last ? out : nullptr);
    }
}

// Round 8
// 1252.106 us; speedup vs baseline: 1.0563x; 1.0563x over previous
//
#include <hip/hip_runtime.h>

// FixPointLayer: z <- tanh(z @ W^T + x), B=8192, F=1024, 50 steps, fp32 out.
// Round 8: round-5 skeleton (single-barrier K-step, 2 blocks/CU, XCD
// mt-grouping, multi-launch ping-pong) but with 64x64 wave tiles:
//   - LDS-read per FLOP (Mw+Nw)/(Mw*Nw): 64x32 = 0.047 B/F (round 5,
//     LDS-BW-bound) -> 64x64 = 0.031 B/F (balanced with MFMA pipe).
//   - 512 blocks x 256 thr (4 waves, 2x2 grid of 64x64); BK=64;
//     64 KB dbuf LDS -> 2 blocks/CU; one s_barrier per K-step.
//   - XOR-preswizzled staging (0 bank conflicts, proven rounds 2-7).

#define F 1024
#define NITER 50

typedef __attribute__((ext_vector_type(4))) _Float16 f16x4;
typedef __attribute__((ext_vector_type(8))) _Float16 f16x8;
typedef __attribute__((ext_vector_type(4))) float f32x4;

__device__ __forceinline__ float ftanh(float s) {
    float e = __expf(2.0f * s);
    return 1.0f - __fdividef(2.0f, e + 1.0f);
}

__device__ __forceinline__ void gload_lds16(const void* g, void* l) {
    __builtin_amdgcn_global_load_lds(
        (const __attribute__((address_space(1))) void*)g,
        (__attribute__((address_space(3))) void*)l, 16, 0, 0);
}

// shared bid -> (mt, nt) mapping (XCD mt-grouping swizzle), 512 blocks
__device__ __forceinline__ void tile_of(int bid, int& mt, int& nt) {
    const int xcd = bid & 7, q = bid >> 3;  // q: 0..63
    mt = xcd * 8 + (q & 7);                 // 0..63
    nt = q >> 3;                            // 0..7
}

// ---- W fp32 -> f16 ----
__global__ void prep_w(const float* __restrict__ W, _Float16* __restrict__ Wh) {
    int i = blockIdx.x * blockDim.x + threadIdx.x;
    float4 wv = ((const float4*)W)[i];
    f16x4 hv = {(_Float16)wv.x, (_Float16)wv.y, (_Float16)wv.z, (_Float16)wv.w};
    ((f16x4*)Wh)[i] = hv;
}

// ---- z0 = tanh(x) -> f16 ----
__global__ void prep_z0(const float* __restrict__ x, _Float16* __restrict__ zb0) {
    int i = blockIdx.x * blockDim.x + threadIdx.x;
    float4 xv = ((const float4*)x)[i];
    f16x4 zv = {(_Float16)ftanh(xv.x), (_Float16)ftanh(xv.y),
                (_Float16)ftanh(xv.z), (_Float16)ftanh(xv.w)};
    ((f16x4*)zb0)[i] = zv;
}

// ---- pack x into per-(block,thread) C-fragment order, f16; slot = bid ----
// IDENTICAL indexing to fixpoint_gemm's epilogue (shared tile_of + formulas).
__global__ void prep_xfr(const float* __restrict__ x, _Float16* __restrict__ xfr) {
    const int bid = blockIdx.x;   // 512
    const int tid = threadIdx.x;  // 256
    int mt, nt;
    tile_of(bid, mt, nt);
    const int w = tid >> 6, l = tid & 63;
    const int wr = w >> 1, wc = w & 1;   // 2x2 wave grid of 64x64
    const int kg = l >> 4, lc16 = l & 15;
    const int gm = mt * 128, gn = nt * 128;
    _Float16* dst = xfr + (((size_t)bid * 256 + tid) << 6);
#pragma unroll
    for (int m = 0; m < 4; ++m)
#pragma unroll
        for (int n = 0; n < 4; ++n) {
            f16x4 v;
#pragma unroll
            for (int j = 0; j < 4; ++j)
                v[j] = (_Float16)x[(size_t)(gm + wr * 64 + m * 16 + kg * 4 + j) * F
                                   + gn + wc * 64 + n * 16 + lc16];
            *(f16x4*)(dst + (m * 4 + n) * 4) = v;
        }
}

// stage a 128x64 f16 tile: 256 thr x 4 x 16B; XOR-preswizzled source,
// linear LDS dest (both-sides involution, proven)
__device__ __forceinline__ void stage_tile(const _Float16* __restrict__ src,
                                           char* dst, int row0, int kb, int tid) {
    const int lc = tid & 7;
    const int rb = tid >> 3;  // 0..31
#pragma unroll
    for (int r = 0; r < 4; ++r) {
        int row = rb + r * 32;  // 0..127
        int cg = lc ^ (row & 7);
        gload_lds16(src + (size_t)(row0 + row) * F + kb + cg * 8,
                    dst + row * 128 + lc * 16);
    }
}

__global__ __launch_bounds__(256, 2) void fixpoint_gemm(
    const _Float16* __restrict__ zin, _Float16* __restrict__ zout,
    const _Float16* __restrict__ Wh, const _Float16* __restrict__ xfr,
    const float* __restrict__ x32, float* __restrict__ out) {

    __shared__ __align__(16) char lds[65536];  // A: 2x16K, B: 2x16K
    char* const ab[2] = {lds, lds + 16384};
    char* const bb[2] = {lds + 32768, lds + 49152};

    const int tid = threadIdx.x;
    const int w = tid >> 6, l = tid & 63;
    const int wr = w >> 1, wc = w & 1;   // 2x2 waves; wave tile 64x64
    const int kg = l >> 4, lc16 = l & 15;
    const int bid = blockIdx.x;          // 512
    int mt, nt;
    tile_of(bid, mt, nt);
    const int gm = mt * 128, gn = nt * 128;

    // prologue: stage K-tile 0 (8 loads outstanding)
    stage_tile(zin, ab[0], gm, 0, tid);
    stage_tile(Wh, bb[0], gn, 0, tid);

    f32x4 acc[4][4];
#pragma unroll
    for (int m = 0; m < 4; ++m)
#pragma unroll
        for (int n = 0; n < 4; ++n) acc[m][n] = (f32x4){0.f, 0.f, 0.f, 0.f};

    int cur = 0;
#pragma unroll
    for (int kt = 0; kt < 16; ++kt) {
        // my tile-kt loads landed (issued last step, covered by its MFMA phase)
        asm volatile("s_waitcnt vmcnt(0)" ::: "memory");
        __builtin_amdgcn_s_barrier();   // all waves' loads landed AND all
        asm volatile("" ::: "memory");  // waves consumed buffer cur^1 (kt-1)
        if (kt < 15) {
            stage_tile(zin, ab[cur ^ 1], gm, (kt + 1) * 64, tid);
            stage_tile(Wh, bb[cur ^ 1], gn, (kt + 1) * 64, tid);
        }
        const char* A = ab[cur];
        const char* B = bb[cur];
#pragma unroll
        for (int kh = 0; kh < 2; ++kh) {
            const int sw = ((kh * 4 + kg) ^ (lc16 & 7)) << 4;
            f16x8 af[4], bf[4];
#pragma unroll
            for (int m = 0; m < 4; ++m)
                af[m] = *(const f16x8*)(A + (wr * 64 + m * 16 + lc16) * 128 + sw);
#pragma unroll
            for (int n = 0; n < 4; ++n)
                bf[n] = *(const f16x8*)(B + (wc * 64 + n * 16 + lc16) * 128 + sw);
            __builtin_amdgcn_s_setprio(1);
#pragma unroll
            for (int m = 0; m < 4; ++m)
#pragma unroll
                for (int n = 0; n < 4; ++n)
                    acc[m][n] = __builtin_amdgcn_mfma_f32_16x16x32_f16(
                        af[m], bf[n], acc[m][n], 0, 0, 0);
            __builtin_amdgcn_s_setprio(0);
        }
        cur ^= 1;
    }

    // ---- epilogue ----
    const bool lastit = (out != nullptr);
    if (!lastit) {
        _Float16 xl[64];
        {
            const f16x8* xp = (const f16x8*)(xfr + (((size_t)bid * 256 + tid) << 6));
#pragma unroll
            for (int qq = 0; qq < 8; ++qq) *(f16x8*)(xl + 8 * qq) = xp[qq];
        }
#pragma unroll
        for (int m = 0; m < 4; ++m)
#pragma unroll
            for (int j = 0; j < 4; ++j) {
                const size_t gr = gm + wr * 64 + m * 16 + kg * 4 + j;
#pragma unroll
                for (int n = 0; n < 4; ++n) {
                    const int gc = gn + wc * 64 + n * 16 + lc16;
                    zout[gr * F + gc] =
                        (_Float16)ftanh(acc[m][n][j] + (float)xl[(m * 4 + n) * 4 + j]);
                }
            }
    } else {
#pragma unroll
        for (int m = 0; m < 4; ++m)
#pragma unroll
            for (int j = 0; j < 4; ++j) {
                const size_t gr = gm + wr * 64 + m * 16 + kg * 4 + j;
#pragma unroll
                for (int n = 0; n < 4; ++n) {
                    const int gc = gn + wc * 64 + n * 16 + lc16;
                    out[gr * F + gc] = ftanh(acc[m][n][j] + x32[gr * F + gc]);
                }
            }
    }
}

extern "C" void kernel_launch(void* const* d_in, const int* in_sizes, int n_in,
                              void* d_out, int out_size, void* d_ws, size_t ws_size,
                              hipStream_t stream) {
    const float* x = (const float*)d_in[0];   // [8192,1024] fp32
    const float* W = (const float*)d_in[1];   // [1024,1024] fp32
    float* out = (float*)d_out;               // final fp32 output
    char* ws = (char*)d_ws;
    _Float16* zb0 = (_Float16*)ws;                   // 16 MiB
    _Float16* zb1 = (_Float16*)(ws + (16u << 20));   // 16 MiB
    _Float16* Wh  = (_Float16*)(ws + (32u << 20));   // 2 MiB
    _Float16* xfr = (_Float16*)(ws + (34u << 20));   // 16 MiB (total 50 MiB)

    prep_w<<<1024, 256, 0, stream>>>(W, Wh);
    prep_z0<<<8192, 256, 0, stream>>>(x, zb0);
    prep_xfr<<<512, 256, 0, stream>>>(x, xfr);
    for (int it = 1; it < NITER; ++it) {
        _Float16* zin  = (it & 1) ? zb0 : zb1;
        _Float16* zout = (it & 1) ? zb1 : zb0;
        bool last = (it == NITER - 1);
        fixpoint_gemm<<<512, 256, 0, stream>>>(zin, zout, Wh, xfr, x,
                                               last ? out : nullptr);
    }
}